// Round 13
// baseline (697.754 us; speedup 1.0000x reference)
//
#include <hip/hip_runtime.h>
#include <stdint.h>

// Fused linear -> logsumexp -> NLL(sum), TOKENS x DMODEL @ (VOCAB x DMODEL)^T.
// Round 13: r6 (best, 370us GEMM) + ONE delta: triple-buffer counted-vmcnt
// with rotated runtime LDS offsets, single rolled loop body.
//  - r12's 3-body loop held 164 VGPR -> 1 wave/SIMD -> 665us. This version
//    keeps r6's per-iteration shape (1 STAGE + 1 COMPUTE) so pressure ~= r6
//    (112 VGPR); buffer selection is 3 rotated uniform ints, not code bodies.
//  - Per iter k: stage(k+2)@ob_s -> compute@ob_c -> vmcnt(6)+s_barrier.
//    End of iter k has stage(k+1)+stage(k+2)=12 loads in flight; vmcnt(6)
//    drains exactly stage(k+1) (FIFO), leaves stage(k+2) flying => ~2 compute
//    phases of latency cover (B-tile L3/HBM first-touch ~450-900cyc).
//    k=14: vmcnt(0) (stage(15) only one in flight). k=15: no wait.
//  - NO launch_bounds min-waves; no persistent operand regs; no full unroll
//    (r7/r10/r11/r12 register-pressure lessons).

#define TOKENS 8192
#define DMODEL 1024
#define VOCAB  32000

// fp8 geometry: block 128x256, 4 waves (2x2), wave tile 64x128
#define NBMF   (TOKENS / 128)   // 64
#define NBNF   (VOCAB / 256)    // 125
#define NWGF   (NBMF * NBNF)    // 8000 = 8 bands x 1000

// fp32 fallback geometry
#define NBM    (TOKENS / 128)
#define NBN    (VOCAB / 128)
#define NWG    (NBM * NBN)
#define CHUNK  (NWG / 8)

typedef float  f32x4   __attribute__((ext_vector_type(4)));
typedef float  f32x16  __attribute__((ext_vector_type(16)));
typedef int    i32x8   __attribute__((ext_vector_type(8)));
typedef __bf16 bf16x8  __attribute__((ext_vector_type(8)));
typedef unsigned short u16;
typedef u16 u16x4 __attribute__((ext_vector_type(4)));

__device__ __forceinline__ u16 f2bf(float f) {
  union { float f; uint32_t u; } v; v.f = f;
  return (u16)((v.u + 0x7FFFu + ((v.u >> 16) & 1u)) >> 16);
}

// fp32 -> OCP e4m3fn, RNE, saturating.
__device__ __forceinline__ uint8_t f2e4m3(float x) {
  union { float f; uint32_t u; } v; v.f = x;
  const uint32_t s = (v.u >> 24) & 0x80u;
  const float ax = fabsf(x);
  if (ax >= 464.f) return (uint8_t)(s | 0x7E);
  if (ax < 0.015625f) {
    const int q = (int)rintf(ax * 512.f);
    return (uint8_t)(s | (uint32_t)q);
  }
  uint32_t u = v.u;
  u += 0x000FFFFFu + ((u >> 20) & 1u);
  const int E = (int)((u >> 23) & 0xFF) - 127;
  const uint32_t m3 = (u >> 20) & 0x7u;
  return (uint8_t)(s | (uint32_t)(((E + 7) << 3) | m3));
}

__device__ __forceinline__ void g2lds16(const void* gsrc, void* ldst) {
  __builtin_amdgcn_global_load_lds(
      (const __attribute__((address_space(1))) uint32_t*)(uintptr_t)gsrc,
      (__attribute__((address_space(3))) uint32_t*)(uintptr_t)ldst,
      16, 0, 0);
}

__device__ __forceinline__ void bar() {
  asm volatile("" ::: "memory");
  __builtin_amdgcn_s_barrier();
  asm volatile("" ::: "memory");
}
template <int N> __device__ __forceinline__ void vmw() {
  if constexpr (N == 6)      asm volatile("s_waitcnt vmcnt(6)" ::: "memory");
  else if constexpr (N == 0) asm volatile("s_waitcnt vmcnt(0)" ::: "memory");
}

// fp32 -> fp8, identity frag-major tiled layout.
// Tile = (row-block rb of NR=2^(log2ts-6) rows) x (kstep kt of 64 k),
// frag regions of 2048B (32 rows x 64 k). Byte x in tile:
//   sub=x>>11; l=(x&2047)>>5; row=rb*NR+sub*32+(l&31); k=kt*64+(l>>5)*32+(x&31).
__global__ void convert_fp8_tiled(const float* __restrict__ in, uint8_t* __restrict__ out,
                                  long long total, int log2ts, float scale) {
  const long long step = (long long)gridDim.x * blockDim.x * 8;
  const int NR = 1 << (log2ts - 6);
  for (long long d = ((long long)blockIdx.x * blockDim.x + threadIdx.x) * 8;
       d < total; d += step) {
    const long long tile = d >> log2ts;
    const int x   = (int)(d & ((1LL << log2ts) - 1));
    const int sub = x >> 11;
    const int rem = x & 2047;
    const int l   = rem >> 5;
    const int rb  = (int)(tile >> 4);
    const int kt  = (int)(tile & 15);
    const int row = rb * NR + sub * 32 + (l & 31);
    const int k   = kt * 64 + (l >> 5) * 32 + (rem & 31);
    const float* src = in + (size_t)row * DMODEL + k;
    const float4 f0 = *(const float4*)src;
    const float4 f1 = *(const float4*)(src + 4);
    uint8_t r[8] = { f2e4m3(f0.x * scale), f2e4m3(f0.y * scale),
                     f2e4m3(f0.z * scale), f2e4m3(f0.w * scale),
                     f2e4m3(f1.x * scale), f2e4m3(f1.y * scale),
                     f2e4m3(f1.z * scale), f2e4m3(f1.w * scale) };
    *(uint64_t*)(out + d) = *(const uint64_t*)r;
  }
}

// ---------------- MX-fp8 fused GEMM + exp-row-sum ----------------
__global__ __launch_bounds__(256)
void gemm_lse_fp8v8(const uint8_t* __restrict__ A8, const uint8_t* __restrict__ B8,
                    float* __restrict__ S) {
  __shared__ uint8_t smem[73728];        // 3 bufs x 24KB (A 8K | B 16K)

  const int lane = threadIdx.x & 63;
  const int wave = threadIdx.x >> 6;         // 0..3
  const int wr = wave >> 1, wc = wave & 1;   // 2x2; wave tile 64x128

  // Supertile XCD map: band owns bm in [band*8, band*8+8), bn-major sweep.
  const int lid  = blockIdx.x;
  const int band = lid & 7;
  const int idx2 = lid >> 3;                 // 0..999
  const int bn   = idx2 >> 3;                // 0..124
  const int bm   = band * 8 + (idx2 & 7);    // 0..63
  const int arow = bm * 128;

  const uint8_t* Asrc = A8 + (size_t)(bm * 16) * 8192;
  const uint8_t* Bsrc = B8 + (size_t)(bn * 16) * 16384;

  f32x16 acc[2][4];
#pragma unroll
  for (int mi = 0; mi < 2; ++mi)
#pragma unroll
    for (int ni = 0; ni < 4; ++ni) acc[mi][ni] = (f32x16)(0.f);

  // Stage kstep t into LDS offset ob: A 8KB (2 issues/thread) + B 16KB (4/thread).
#define STAGE(ob, t)                                                         \
  {                                                                          \
    _Pragma("unroll")                                                        \
    for (int p = 0; p < 2; ++p) {                                            \
      const int c = p * 4 + wave;                                            \
      g2lds16(Asrc + (size_t)(t) * 8192 + c * 1024 + lane * 16,              \
              (void*)(&smem[(ob) + c * 1024]));                              \
    }                                                                        \
    _Pragma("unroll")                                                        \
    for (int p = 0; p < 4; ++p) {                                            \
      const int c = p * 4 + wave;                                            \
      g2lds16(Bsrc + (size_t)(t) * 16384 + c * 1024 + lane * 16,             \
              (void*)(&smem[(ob) + 8192 + c * 1024]));                       \
    }                                                                        \
  }

#define COMPUTE(ob)                                                          \
  {                                                                          \
    const uint8_t* ap = &smem[(ob) + (wr * 2) * 2048] + lane * 32;           \
    const uint8_t* bp = &smem[(ob) + 8192 + (wc * 4) * 2048] + lane * 32;    \
    i32x8 a[2], b[4];                                                        \
    _Pragma("unroll")                                                        \
    for (int mi = 0; mi < 2; ++mi) a[mi] = *(const i32x8*)(ap + mi * 2048);  \
    _Pragma("unroll")                                                        \
    for (int ni = 0; ni < 4; ++ni) b[ni] = *(const i32x8*)(bp + ni * 2048);  \
    __builtin_amdgcn_s_setprio(1);                                           \
    _Pragma("unroll")                                                        \
    for (int mi = 0; mi < 2; ++mi) {                                         \
      _Pragma("unroll")                                                      \
      for (int ni = 0; ni < 4; ++ni)                                         \
        acc[mi][ni] = __builtin_amdgcn_mfma_scale_f32_32x32x64_f8f6f4(       \
            a[mi], b[ni], acc[mi][ni], 0, 0,                                 \
            0, 0x7F7F7F7F, 0, 0x7F7F7F7F);                                   \
    }                                                                        \
    __builtin_amdgcn_s_setprio(0);                                           \
  }

  // Prologue: stage(0)->buf0, stage(1)->buf1; vmcnt(6) => stage(0) landed.
  STAGE(0, 0)
  STAGE(24576, 1)
  vmw<6>();
  bar();

  // Rotated buffer offsets: compute@ob_c, next@ob_n, stage-target@ob_s.
  int ob_c = 0, ob_n = 24576, ob_s = 49152;

#pragma unroll 1
  for (int k = 0; k < 16; ++k) {
    if (k < 14) STAGE(ob_s, k + 2)   // overwrites buf[(k-1)%3]; its readers
                                     // passed the previous end-of-iter barrier
    COMPUTE(ob_c)
    if (k < 14) {                    // stage(k+1) landed; stage(k+2) in flight
      vmw<6>();
      bar();
    } else if (k == 14) {            // drain stage(15)
      vmw<0>();
      bar();
    }
    const int tmp = ob_c; ob_c = ob_n; ob_n = ob_s; ob_s = tmp;
  }
#undef STAGE
#undef COMPUTE

  // Epilogue: 32x32 C/D layout (m101-verified): col = lane&31,
  // row = (reg&3) + 8*(reg>>2) + 4*(lane>>5). Unscale 1/16 (W was x16).
#pragma unroll
  for (int mi = 0; mi < 2; ++mi) {
#pragma unroll
    for (int r = 0; r < 16; ++r) {
      float v = 0.f;
#pragma unroll
      for (int ni = 0; ni < 4; ++ni) v += __expf(acc[mi][ni][r] * 0.0625f);
      v += __shfl_xor(v, 1);
      v += __shfl_xor(v, 2);
      v += __shfl_xor(v, 4);
      v += __shfl_xor(v, 8);
      v += __shfl_xor(v, 16);
      if ((lane & 31) == 0) {
        const int row = arow + wr * 64 + mi * 32 + (r & 3) + 8 * (r >> 2) + 4 * (lane >> 5);
        atomicAdd(&S[row], v);
      }
    }
  }
}

// ---------------- 128^2 fp32 fallback (ws too small), unchanged ----------------
__global__ __launch_bounds__(256)
void gemm_lse_fb(const float* __restrict__ Af, const float* __restrict__ Bf,
                 float* __restrict__ S) {
  __shared__ u16 As[128 * 64];
  __shared__ u16 Bs[128 * 64];

  const int tid  = threadIdx.x;
  const int lane = tid & 63;
  const int wave = tid >> 6;
  const int wr = wave >> 1, wc = wave & 1;
  const int l15 = lane & 15, l4 = lane >> 4;

  const int lid = blockIdx.x;
  const int wid = (lid & 7) * CHUNK + (lid >> 3);
  const int bm = wid & (NBM - 1);
  const int bn = wid / NBM;

  f32x4 acc[4][4];
#pragma unroll
  for (int m = 0; m < 4; ++m)
#pragma unroll
    for (int n = 0; n < 4; ++n) acc[m][n] = (f32x4)(0.f);

  for (int kt = 0; kt < DMODEL / 64; ++kt) {
    const int k0 = kt * 64;
    {
      const int row = tid >> 4;
      const int kq  = (tid & 15) * 4;
#pragma unroll
      for (int r = 0; r < 8; ++r) {
        const int rr = r * 16 + row;
        const int kd = kq ^ ((rr & 7) << 3);
        float4 a4 = *(const float4*)(Af + (size_t)(bm * 128 + rr) * DMODEL + k0 + kq);
        float4 b4 = *(const float4*)(Bf + (size_t)(bn * 128 + rr) * DMODEL + k0 + kq);
        u16x4 ap = { f2bf(a4.x), f2bf(a4.y), f2bf(a4.z), f2bf(a4.w) };
        u16x4 bp = { f2bf(b4.x), f2bf(b4.y), f2bf(b4.z), f2bf(b4.w) };
        *(u16x4*)&As[rr * 64 + kd] = ap;
        *(u16x4*)&Bs[rr * 64 + kd] = bp;
      }
    }
    __syncthreads();
#pragma unroll
    for (int kk = 0; kk < 2; ++kk) {
      bf16x8 av[4], bv[4];
      const int swz = (l15 & 7) << 3;
      const int kc  = (kk * 32 + l4 * 8) ^ swz;
#pragma unroll
      for (int m = 0; m < 4; ++m)
        av[m] = *(const bf16x8*)&As[(wr * 64 + m * 16 + l15) * 64 + kc];
#pragma unroll
      for (int n = 0; n < 4; ++n)
        bv[n] = *(const bf16x8*)&Bs[(wc * 64 + n * 16 + l15) * 64 + kc];
#pragma unroll
      for (int m = 0; m < 4; ++m)
#pragma unroll
        for (int n = 0; n < 4; ++n)
          acc[m][n] = __builtin_amdgcn_mfma_f32_16x16x32_bf16(av[m], bv[n], acc[m][n], 0, 0, 0);
    }
    __syncthreads();
  }

#pragma unroll
  for (int m = 0; m < 4; ++m) {
#pragma unroll
    for (int j = 0; j < 4; ++j) {
      float v = 0.f;
#pragma unroll
      for (int n = 0; n < 4; ++n) v += __expf(acc[m][n][j]);
      v += __shfl_xor(v, 1);
      v += __shfl_xor(v, 2);
      v += __shfl_xor(v, 4);
      v += __shfl_xor(v, 8);
      if (l15 == 0) {
        const int row = bm * 128 + wr * 64 + m * 16 + l4 * 4 + j;
        atomicAdd(&S[row], v);
      }
    }
  }
}

// ---------------- exact fp32 target score ----------------
__global__ void target_score_k(const float* __restrict__ inp, const float* __restrict__ W,
                               const int* __restrict__ tgt, float* __restrict__ ts) {
  const int gtid = blockIdx.x * blockDim.x + threadIdx.x;
  const int t = gtid >> 6;
  const int lane = threadIdx.x & 63;
  if (t >= TOKENS) return;
  bool allhi0 = true, anylo = false;
  for (int i = 0; i < 64; ++i) {
    if (tgt[2 * i + 1] != 0) allhi0 = false;
    if (tgt[2 * i] != 0) anylo = true;
  }
  const int v = (allhi0 && anylo) ? tgt[2 * t] : tgt[t];
  const float4* xr = (const float4*)(inp + (size_t)t * DMODEL);
  const float4* wr = (const float4*)(W + (size_t)v * DMODEL);
  float s = 0.f;
#pragma unroll
  for (int i = 0; i < 4; ++i) {
    float4 a = xr[lane + 64 * i];
    float4 b = wr[lane + 64 * i];
    s += a.x * b.x + a.y * b.y + a.z * b.z + a.w * b.w;
  }
#pragma unroll
  for (int off = 32; off >= 1; off >>= 1) s += __shfl_xor(s, off);
  if (lane == 0) ts[t] = s;
}

__global__ void finalize_k(const float* __restrict__ S, const float* __restrict__ ts,
                           float* __restrict__ out) {
  __shared__ float red[16];
  float s = 0.f;
  for (int t = threadIdx.x; t < TOKENS; t += blockDim.x) s += __logf(S[t]) - ts[t];
#pragma unroll
  for (int off = 32; off >= 1; off >>= 1) s += __shfl_xor(s, off);
  const int wave = threadIdx.x >> 6, lane = threadIdx.x & 63;
  if (lane == 0) red[wave] = s;
  __syncthreads();
  if (threadIdx.x == 0) {
    float tot = 0.f;
    for (int w = 0; w < (int)(blockDim.x >> 6); ++w) tot += red[w];
    out[0] = tot;
  }
}

extern "C" void kernel_launch(void* const* d_in, const int* in_sizes, int n_in,
                              void* d_out, int out_size, void* d_ws, size_t ws_size,
                              hipStream_t stream) {
  const float* inp = (const float*)d_in[0];
  const float* W   = (const float*)d_in[1];
  const int*   tgt = (const int*)d_in[2];
  float* out = (float*)d_out;

  char* ws = (char*)d_ws;
  float* S  = (float*)ws;
  float* ts = (float*)(ws + 32 * 1024);
  const size_t offA = 64 * 1024;
  const long long totalA = (long long)TOKENS * DMODEL;   // 8,388,608 bytes fp8
  const long long totalB = (long long)VOCAB * DMODEL;    // 32,768,000 bytes fp8
  const size_t offB = offA + (size_t)totalA;
  const size_t need = offB + (size_t)totalB;             // ~41.2 MB
  const bool preconv = ws_size >= need;

  hipMemsetAsync(S, 0, TOKENS * sizeof(float), stream);

  if (preconv) {
    uint8_t* A8 = (uint8_t*)(ws + offA);
    uint8_t* B8 = (uint8_t*)(ws + offB);
    convert_fp8_tiled<<<4096, 256, 0, stream>>>(inp, A8, totalA, 13, 1.0f);
    convert_fp8_tiled<<<16000, 256, 0, stream>>>(W, B8, totalB, 14, 16.0f);
    gemm_lse_fp8v8<<<NWGF, 256, 0, stream>>>(A8, B8, S);
  } else {
    gemm_lse_fb<<<NWG, 256, 0, stream>>>(inp, W, S);
  }
  target_score_k<<<(TOKENS * 64) / 256, 256, 0, stream>>>(inp, W, tgt, ts);
  finalize_k<<<1, 1024, 0, stream>>>(S, ts, out);
}

// Round 14
// 376.342 us; speedup vs baseline: 1.8540x; 1.8540x over previous
//
#include <hip/hip_runtime.h>
#include <stdint.h>

// Fused linear -> logsumexp -> NLL(sum), TOKENS x DMODEL @ (VOCAB x DMODEL)^T.
// Round 14: REVERT to round-6 kernel verbatim -- the measured best (376us).
// Session conclusion: r6's 2-buffer/2-barrier MX-fp8 structure at 240 unified
// regs (112 VGPR + 128 AGPR acc) sits just under the 256-reg occupancy cliff.
// Every deeper-pipeline variant (r7,r9-r13) either spilled or crossed the
// cliff to 1 wave/SIMD; smaller-acc variants (r8) halve MFMA-per-barrier and
// measured worse. This is the constrained optimum of this design space.

#define TOKENS 8192
#define DMODEL 1024
#define VOCAB  32000

// fp8 main geometry
#define NBM32  (TOKENS / 128)   // 64
#define NBN32  (VOCAB / 256)    // 125
#define NWG32  (NBM32 * NBN32)  // 8000 = 8 bands x 1000

// fp32 fallback geometry
#define NBM    (TOKENS / 128)
#define NBN    (VOCAB / 128)
#define NWG    (NBM * NBN)
#define CHUNK  (NWG / 8)

typedef float  f32x4   __attribute__((ext_vector_type(4)));
typedef float  f32x16  __attribute__((ext_vector_type(16)));
typedef int    i32x8   __attribute__((ext_vector_type(8)));
typedef __bf16 bf16x8  __attribute__((ext_vector_type(8)));
typedef unsigned short u16;
typedef u16 u16x4 __attribute__((ext_vector_type(4)));

__device__ __forceinline__ u16 f2bf(float f) {
  union { float f; uint32_t u; } v; v.f = f;
  return (u16)((v.u + 0x7FFFu + ((v.u >> 16) & 1u)) >> 16);
}

// fp32 -> OCP e4m3fn, RNE, saturating.
__device__ __forceinline__ uint8_t f2e4m3(float x) {
  union { float f; uint32_t u; } v; v.f = x;
  const uint32_t s = (v.u >> 24) & 0x80u;
  const float ax = fabsf(x);
  if (ax >= 464.f) return (uint8_t)(s | 0x7E);
  if (ax < 0.015625f) {
    const int q = (int)rintf(ax * 512.f);
    return (uint8_t)(s | (uint32_t)q);
  }
  uint32_t u = v.u;
  u += 0x000FFFFFu + ((u >> 20) & 1u);
  const int E = (int)((u >> 23) & 0xFF) - 127;
  const uint32_t m3 = (u >> 20) & 0x7u;
  return (uint8_t)(s | (uint32_t)(((E + 7) << 3) | m3));
}

__device__ __forceinline__ void g2lds16(const void* gsrc, void* ldst) {
  __builtin_amdgcn_global_load_lds(
      (const __attribute__((address_space(1))) uint32_t*)(uintptr_t)gsrc,
      (__attribute__((address_space(3))) uint32_t*)(uintptr_t)ldst,
      16, 0, 0);
}

// fp32 -> fp8, writing the frag-major tiled layout (identity slot order).
// Tile = (row-block rb of NR rows) x (kstep kt of 64 k): size 2^log2ts bytes.
// Within tile: byte = sub*2048 + l*32 + b, where sub = (row%NR)/32,
// l = (row&31) + 32*((k%64)>>5), b = k&31.
__global__ void convert_fp8_tiled(const float* __restrict__ in, uint8_t* __restrict__ out,
                                  long long total, int NR, int log2ts, float scale) {
  const long long step = (long long)gridDim.x * blockDim.x * 8;
  for (long long d = ((long long)blockIdx.x * blockDim.x + threadIdx.x) * 8;
       d < total; d += step) {
    const long long tile = d >> log2ts;
    const int x  = (int)(d & ((1 << log2ts) - 1));
    const int sub = x >> 11;
    const int rem = x & 2047;
    const int l   = rem >> 5;
    const int rb  = (int)(tile >> 4);
    const int kt  = (int)(tile & 15);
    const int row = rb * NR + sub * 32 + (l & 31);
    const int k   = kt * 64 + (l >> 5) * 32 + (rem & 31);
    const float* src = in + (size_t)row * DMODEL + k;
    const float4 f0 = *(const float4*)src;
    const float4 f1 = *(const float4*)(src + 4);
    uint8_t r[8] = { f2e4m3(f0.x * scale), f2e4m3(f0.y * scale),
                     f2e4m3(f0.z * scale), f2e4m3(f0.w * scale),
                     f2e4m3(f1.x * scale), f2e4m3(f1.y * scale),
                     f2e4m3(f1.z * scale), f2e4m3(f1.w * scale) };
    *(uint64_t*)(out + d) = *(const uint64_t*)r;
  }
}

// ---------------- MX-fp8 32x32 fused GEMM + exp-row-sum ----------------
// Identity linear staging: tile data already in LDS-final order.
template <int NCHUNK>
__device__ __forceinline__ void stage_lin(const uint8_t* __restrict__ src, uint8_t* dst,
                                          int wave, int lane) {
#pragma unroll
  for (int p = 0; p < NCHUNK / 4; ++p) {
    const int c = p * 4 + wave;
    g2lds16(src + c * 1024 + lane * 16, (void*)(dst + c * 1024));
  }
}

__device__ __forceinline__ void kstep32(const uint8_t* As, const uint8_t* Bs,
                                        f32x16 (&acc)[2][4],
                                        int wr, int wc, int lane) {
  i32x8 a[2], b[4];
  const uint8_t* ap = As + (wr * 2) * 2048 + lane * 32;
#pragma unroll
  for (int mi = 0; mi < 2; ++mi) {
    *(uint4*)&a[mi]       = *(const uint4*)(ap + mi * 2048);
    *((uint4*)&a[mi] + 1) = *(const uint4*)(ap + mi * 2048 + 16);
  }
  const uint8_t* bp = Bs + (wc * 4) * 2048 + lane * 32;
#pragma unroll
  for (int ni = 0; ni < 4; ++ni) {
    *(uint4*)&b[ni]       = *(const uint4*)(bp + ni * 2048);
    *((uint4*)&b[ni] + 1) = *(const uint4*)(bp + ni * 2048 + 16);
  }
  __builtin_amdgcn_s_setprio(1);
#pragma unroll
  for (int mi = 0; mi < 2; ++mi)
#pragma unroll
    for (int ni = 0; ni < 4; ++ni)
      acc[mi][ni] = __builtin_amdgcn_mfma_scale_f32_32x32x64_f8f6f4(
          a[mi], b[ni], acc[mi][ni], 0, 0,
          0, 0x7F7F7F7F, 0, 0x7F7F7F7F);
  __builtin_amdgcn_s_setprio(0);
}

__global__ __launch_bounds__(256, 2)
void gemm_lse_fp8v2(const uint8_t* __restrict__ A8, const uint8_t* __restrict__ B8,
                    float* __restrict__ S) {
  __shared__ uint8_t smem[49152];        // 48 KiB: A0 8K | B0 16K | A1 8K | B1 16K
  uint8_t* A0 = smem;
  uint8_t* B0 = smem + 8192;
  uint8_t* A1 = smem + 24576;
  uint8_t* B1 = smem + 32768;

  const int tid  = threadIdx.x;
  const int lane = tid & 63;
  const int wave = tid >> 6;                 // 0..3
  const int wr = wave >> 1, wc = wave & 1;   // 2x2 wave grid; wave tile 64x128

  // Supertile XCD map: band owns bm in [band*8, band*8+8), bn-major sweep.
  const int lid  = blockIdx.x;
  const int band = lid & 7;
  const int idx2 = lid >> 3;                 // 0..999
  const int bn   = idx2 >> 3;                // 0..124
  const int bm   = band * 8 + (idx2 & 7);    // 0..63
  const int arow = bm * 128;

  const uint8_t* Abase = A8 + (size_t)(bm * 16) * 8192;
  const uint8_t* Bbase = B8 + (size_t)(bn * 16) * 16384;

  f32x16 acc[2][4];
#pragma unroll
  for (int mi = 0; mi < 2; ++mi)
#pragma unroll
    for (int ni = 0; ni < 4; ++ni) acc[mi][ni] = (f32x16)(0.f);

  // prologue: stage kstep 0 into buf0
  stage_lin<8>(Abase, A0, wave, lane);
  stage_lin<16>(Bbase, B0, wave, lane);

  // 16 ksteps of K=64, unrolled x2 for compile-time buffer pointers.
#pragma unroll 1
  for (int tt = 0; tt < 8; ++tt) {
    const int t0 = 2 * tt;
    __syncthreads();
    if (t0 + 1 < 16) {
      stage_lin<8>(Abase + (size_t)(t0 + 1) * 8192, A1, wave, lane);
      stage_lin<16>(Bbase + (size_t)(t0 + 1) * 16384, B1, wave, lane);
    }
    kstep32(A0, B0, acc, wr, wc, lane);
    __syncthreads();
    if (t0 + 2 < 16) {
      stage_lin<8>(Abase + (size_t)(t0 + 2) * 8192, A0, wave, lane);
      stage_lin<16>(Bbase + (size_t)(t0 + 2) * 16384, B0, wave, lane);
    }
    kstep32(A1, B1, acc, wr, wc, lane);
  }

  // Epilogue: 32x32 C/D layout (m101-verified): col = lane&31,
  // row = (reg&3) + 8*(reg>>2) + 4*(lane>>5). Unscale 1/16 (W was x16).
#pragma unroll
  for (int mi = 0; mi < 2; ++mi) {
#pragma unroll
    for (int r = 0; r < 16; ++r) {
      float v = 0.f;
#pragma unroll
      for (int ni = 0; ni < 4; ++ni) v += __expf(acc[mi][ni][r] * 0.0625f);
      v += __shfl_xor(v, 1);
      v += __shfl_xor(v, 2);
      v += __shfl_xor(v, 4);
      v += __shfl_xor(v, 8);
      v += __shfl_xor(v, 16);
      if ((lane & 31) == 0) {
        const int row = arow + (wr * 2 + mi) * 32 + (r & 3) + 8 * (r >> 2) + 4 * (lane >> 5);
        atomicAdd(&S[row], v);
      }
    }
  }
}

// ---------------- 128^2 fp32 fallback (ws too small), unchanged ----------------
__global__ __launch_bounds__(256)
void gemm_lse_fb(const float* __restrict__ Af, const float* __restrict__ Bf,
                 float* __restrict__ S) {
  __shared__ u16 As[128 * 64];
  __shared__ u16 Bs[128 * 64];

  const int tid  = threadIdx.x;
  const int lane = tid & 63;
  const int wave = tid >> 6;
  const int wr = wave >> 1, wc = wave & 1;
  const int l15 = lane & 15, l4 = lane >> 4;

  const int lid = blockIdx.x;
  const int wid = (lid & 7) * CHUNK + (lid >> 3);
  const int bm = wid & (NBM - 1);
  const int bn = wid / NBM;

  f32x4 acc[4][4];
#pragma unroll
  for (int m = 0; m < 4; ++m)
#pragma unroll
    for (int n = 0; n < 4; ++n) acc[m][n] = (f32x4)(0.f);

  for (int kt = 0; kt < DMODEL / 64; ++kt) {
    const int k0 = kt * 64;
    {
      const int row = tid >> 4;
      const int kq  = (tid & 15) * 4;
#pragma unroll
      for (int r = 0; r < 8; ++r) {
        const int rr = r * 16 + row;
        const int kd = kq ^ ((rr & 7) << 3);
        float4 a4 = *(const float4*)(Af + (size_t)(bm * 128 + rr) * DMODEL + k0 + kq);
        float4 b4 = *(const float4*)(Bf + (size_t)(bn * 128 + rr) * DMODEL + k0 + kq);
        u16x4 ap = { f2bf(a4.x), f2bf(a4.y), f2bf(a4.z), f2bf(a4.w) };
        u16x4 bp = { f2bf(b4.x), f2bf(b4.y), f2bf(b4.z), f2bf(b4.w) };
        *(u16x4*)&As[rr * 64 + kd] = ap;
        *(u16x4*)&Bs[rr * 64 + kd] = bp;
      }
    }
    __syncthreads();
#pragma unroll
    for (int kk = 0; kk < 2; ++kk) {
      bf16x8 av[4], bv[4];
      const int swz = (l15 & 7) << 3;
      const int kc  = (kk * 32 + l4 * 8) ^ swz;
#pragma unroll
      for (int m = 0; m < 4; ++m)
        av[m] = *(const bf16x8*)&As[(wr * 64 + m * 16 + l15) * 64 + kc];
#pragma unroll
      for (int n = 0; n < 4; ++n)
        bv[n] = *(const bf16x8*)&Bs[(wc * 64 + n * 16 + l15) * 64 + kc];
#pragma unroll
      for (int m = 0; m < 4; ++m)
#pragma unroll
        for (int n = 0; n < 4; ++n)
          acc[m][n] = __builtin_amdgcn_mfma_f32_16x16x32_bf16(av[m], bv[n], acc[m][n], 0, 0, 0);
    }
    __syncthreads();
  }

#pragma unroll
  for (int m = 0; m < 4; ++m) {
#pragma unroll
    for (int j = 0; j < 4; ++j) {
      float v = 0.f;
#pragma unroll
      for (int n = 0; n < 4; ++n) v += __expf(acc[m][n][j]);
      v += __shfl_xor(v, 1);
      v += __shfl_xor(v, 2);
      v += __shfl_xor(v, 4);
      v += __shfl_xor(v, 8);
      if (l15 == 0) {
        const int row = bm * 128 + wr * 64 + m * 16 + l4 * 4 + j;
        atomicAdd(&S[row], v);
      }
    }
  }
}

// ---------------- exact fp32 target score ----------------
__global__ void target_score_k(const float* __restrict__ inp, const float* __restrict__ W,
                               const int* __restrict__ tgt, float* __restrict__ ts) {
  const int gtid = blockIdx.x * blockDim.x + threadIdx.x;
  const int t = gtid >> 6;
  const int lane = threadIdx.x & 63;
  if (t >= TOKENS) return;
  bool allhi0 = true, anylo = false;
  for (int i = 0; i < 64; ++i) {
    if (tgt[2 * i + 1] != 0) allhi0 = false;
    if (tgt[2 * i] != 0) anylo = true;
  }
  const int v = (allhi0 && anylo) ? tgt[2 * t] : tgt[t];
  const float4* xr = (const float4*)(inp + (size_t)t * DMODEL);
  const float4* wr = (const float4*)(W + (size_t)v * DMODEL);
  float s = 0.f;
#pragma unroll
  for (int i = 0; i < 4; ++i) {
    float4 a = xr[lane + 64 * i];
    float4 b = wr[lane + 64 * i];
    s += a.x * b.x + a.y * b.y + a.z * b.z + a.w * b.w;
  }
#pragma unroll
  for (int off = 32; off >= 1; off >>= 1) s += __shfl_xor(s, off);
  if (lane == 0) ts[t] = s;
}

__global__ void finalize_k(const float* __restrict__ S, const float* __restrict__ ts,
                           float* __restrict__ out) {
  __shared__ float red[16];
  float s = 0.f;
  for (int t = threadIdx.x; t < TOKENS; t += blockDim.x) s += __logf(S[t]) - ts[t];
#pragma unroll
  for (int off = 32; off >= 1; off >>= 1) s += __shfl_xor(s, off);
  const int wave = threadIdx.x >> 6, lane = threadIdx.x & 63;
  if (lane == 0) red[wave] = s;
  __syncthreads();
  if (threadIdx.x == 0) {
    float tot = 0.f;
    for (int w = 0; w < (int)(blockDim.x >> 6); ++w) tot += red[w];
    out[0] = tot;
  }
}

extern "C" void kernel_launch(void* const* d_in, const int* in_sizes, int n_in,
                              void* d_out, int out_size, void* d_ws, size_t ws_size,
                              hipStream_t stream) {
  const float* inp = (const float*)d_in[0];
  const float* W   = (const float*)d_in[1];
  const int*   tgt = (const int*)d_in[2];
  float* out = (float*)d_out;

  char* ws = (char*)d_ws;
  float* S  = (float*)ws;
  float* ts = (float*)(ws + 32 * 1024);
  const size_t offA = 64 * 1024;
  const long long totalA = (long long)TOKENS * DMODEL;   // 8,388,608 bytes fp8
  const long long totalB = (long long)VOCAB * DMODEL;    // 32,768,000 bytes fp8
  const size_t offB = offA + (size_t)totalA;
  const size_t need = offB + (size_t)totalB;             // ~41.2 MB
  const bool preconv = ws_size >= need;

  hipMemsetAsync(S, 0, TOKENS * sizeof(float), stream);

  if (preconv) {
    uint8_t* A8 = (uint8_t*)(ws + offA);
    uint8_t* B8 = (uint8_t*)(ws + offB);
    convert_fp8_tiled<<<4096, 256, 0, stream>>>(inp, A8, totalA, 128, 13, 1.0f);
    convert_fp8_tiled<<<16000, 256, 0, stream>>>(W, B8, totalB, 256, 14, 16.0f);
    gemm_lse_fp8v2<<<NWG32, 256, 0, stream>>>(A8, B8, S);
  } else {
    gemm_lse_fb<<<NWG, 256, 0, stream>>>(inp, W, S);
  }
  target_score_k<<<(TOKENS * 64) / 256, 256, 0, stream>>>(inp, W, tgt, ts);
  finalize_k<<<1, 1024, 0, stream>>>(S, ts, out);
}